// Round 18
// baseline (115.162 us; speedup 1.0000x reference)
//
#include <hip/hip_runtime.h>
#include <math.h>

// DynamicSparseAttention via MFMA flash (f16 operands, fp32 accum):
// out = (O5 + Z^4 O1) / (S5 + Z^4 S1), e = 2^(s*log2e - m'), Z = S1.
// R18: 16x16x32 MFMA, 16 q/wave, 8-wave/512-thr blocks -> 4096 waves =
//   4 waves/SIMD (2x TLP) with NO redundant staging (same tiles/block).
//   P exchange via wave-private LDS round-trip (R2-verified layouts).

typedef _Float16 h8 __attribute__((ext_vector_type(8)));
typedef _Float16 h4 __attribute__((ext_vector_type(4)));
typedef _Float16 h2 __attribute__((ext_vector_type(2)));
typedef __fp16 g2 __attribute__((ext_vector_type(2)));
typedef float f4 __attribute__((ext_vector_type(4)));
typedef unsigned int u4v __attribute__((ext_vector_type(4)));

constexpr int Sc = 2048, Hc = 16;
constexpr int KB = 64, NT = Sc / KB;
constexpr float LOG2E = 1.4426950408889634f;

__device__ __forceinline__ f4 mm16(h8 a, h8 b, f4 c) {
  return __builtin_amdgcn_mfma_f32_16x16x32_f16(a, b, c, 0, 0, 0);
}
__device__ __forceinline__ unsigned pku(float a, float b) {
  return __builtin_bit_cast(unsigned, __builtin_amdgcn_cvt_pkrtz(a, b));
}
__device__ __forceinline__ float fdot2(h2 a, float c) {  // a.x + a.y + c
  const g2 one2 = {(__fp16)1.0f, (__fp16)1.0f};
  return __builtin_amdgcn_fdot2(__builtin_bit_cast(g2, a), one2, c, false);
}

__global__ __launch_bounds__(512, 2) void dsa_mfma(
    const float* __restrict__ Q, const float* __restrict__ K,
    const float* __restrict__ V, float* __restrict__ O) {
  __shared__ __align__(16) _Float16 kv[2][2][64 * 64];   // [buf][K|V], 32 KB
  __shared__ __align__(16) _Float16 Ps[8][2][16 * 64];   // per-wave P (e,e5), 32 KB

  const int tid = threadIdx.x;
  const int w = tid >> 6, lane = tid & 63, lq = lane & 15, lg = lane >> 4;
  const int kxor = (lq & 7) << 3;

  // XCD-bijective swizzle: 512 blocks = 8 XCD x 64; each XCD owns 4 heads.
  const int blk = blockIdx.x;
  const int ww = (blk & 7) * 64 + (blk >> 3);
  const int qtb = ww & 15, bh = ww >> 4;
  const int b = bh >> 4, h = bh & 15;

  const size_t base = ((size_t)b * Sc * Hc + h) * 64;  // row stride = 1024 floats
  const float* Qb = Q + base;
  const float* Kb = K + base;
  const float* Vb = V + base;
  const int q0 = qtb * 128 + w * 16;

  // ---- Q fragments (B-operand): lane holds Q[q0+lq][ks*32 + lg*8 + j]*log2e ----
  h8 qf[2];
#pragma unroll
  for (int ks = 0; ks < 2; ++ks) {
    const float* p = Qb + (size_t)(q0 + lq) * 1024 + ks * 32 + lg * 8;
    f4 a = *(const f4*)p, c = *(const f4*)(p + 4);
#pragma unroll
    for (int i = 0; i < 4; ++i) {
      qf[ks][i] = (_Float16)(a[i] * LOG2E);
      qf[ks][4 + i] = (_Float16)(c[i] * LOG2E);
    }
  }

  f4 O1[4] = {}, O5[4] = {};  // O[q][d]: C-frag per dtile
  float S1p = 0.f, S5p = 0.f, mr = -INFINITY;

  // ---- staging (512 threads, half of R16 per thread) ----
  f4 kf[2];
  float vreg[8];
  // K: row = lane, f32 col-octet = w (cols w*8..w*8+7)
  // V: d-col = lane, k-octet = w (k = w*8..w*8+7)
  auto LOADK = [&](int k0) {
    const float* p = Kb + (size_t)(k0 + lane) * 1024 + w * 8;
    kf[0] = *(const f4*)p;
    kf[1] = *(const f4*)(p + 4);
  };
  auto LOADV = [&](int k0) {  // coalesced: 64 lanes read consecutive d
    const float* p = Vb + (size_t)(k0 + w * 8) * 1024 + lane;
#pragma unroll
    for (int j = 0; j < 8; ++j) vreg[j] = p[(size_t)j * 1024];
  };
  auto STORE = [&](int buf) {
    _Float16* Ks = &kv[buf][0][0];
    _Float16* Vts = &kv[buf][1][0];
    u4v kw = {pku(kf[0][0], kf[0][1]), pku(kf[0][2], kf[0][3]),
              pku(kf[1][0], kf[1][1]), pku(kf[1][2], kf[1][3])};
    int kcol = (w * 8) ^ ((lane & 7) << 3);
    *(h8*)&Ks[lane * 64 + kcol] = __builtin_bit_cast(h8, kw);
    u4v vw = {pku(vreg[0], vreg[1]), pku(vreg[2], vreg[3]),
              pku(vreg[4], vreg[5]), pku(vreg[6], vreg[7])};
    int vcol = (w * 8) ^ ((lane & 7) << 3);
    *(h8*)&Vts[lane * 64 + vcol] = __builtin_bit_cast(h8, vw);
  };

  // ---- prologue ----
  LOADK(0);
  LOADV(0);
  STORE(0);
  LOADK(KB);
  LOADV(KB);
  __syncthreads();

  // ---- main loop: 1 tile per barrier, 2 KV buffers ----
#pragma unroll 1
  for (int t = 0; t < NT; ++t) {
    const int cur = t & 1;
    if (t + 1 < NT) STORE(cur ^ 1);  // regs(t+1) -> idle buffer
    if (t + 2 < NT) {
      LOADK((t + 2) * KB);
      LOADV((t + 2) * KB);
    }

    // ---- QK^T (swapped): sc[mt] = S[k = mt*16 + lg*4 + r][q = lq] ----
    const _Float16* Ks = &kv[cur][0][0];
    f4 sc[4];
#pragma unroll
    for (int mt = 0; mt < 4; ++mt) sc[mt] = f4{};
    __builtin_amdgcn_s_setprio(1);
#pragma unroll
    for (int ks = 0; ks < 2; ++ks)
#pragma unroll
      for (int mt = 0; mt < 4; ++mt) {
        h8 a = *(const h8*)&Ks[(mt * 16 + lq) * 64 + ((ks * 32 + lg * 8) ^ kxor)];
        sc[mt] = mm16(a, qf[ks], sc[mt]);
      }
    __builtin_amdgcn_s_setprio(0);

    // ---- tile max (16 per lane) + cross-lane over lg groups ----
    float m4[4];
#pragma unroll
    for (int mt = 0; mt < 4; ++mt)
      m4[mt] = fmaxf(fmaxf(sc[mt][0], sc[mt][1]), fmaxf(sc[mt][2], sc[mt][3]));
    float tm = fmaxf(fmaxf(m4[0], m4[1]), fmaxf(m4[2], m4[3]));
    tm = fmaxf(tm, __shfl_xor(tm, 16));
    tm = fmaxf(tm, __shfl_xor(tm, 32));
    if (__any(tm > mr)) {
      float nm = fmaxf(mr, tm);
      float f = __builtin_amdgcn_exp2f(mr - nm);
      float f2 = f * f, f5 = f2 * f2 * f;
      mr = nm;
      S1p *= f;
      S5p *= f5;
#pragma unroll
      for (int dt = 0; dt < 4; ++dt) {
        O1[dt] *= f;
        O5[dt] *= f5;
      }
    }
    // skip e5 consumption iff 5*(tm-mr) <= -24.5: all f16 e^5 are exact +0
    const bool do5 = __any(tm > mr - 4.9f);

    // ---- exp, P (e and e^5) to wave-private LDS; S1 partial via fdot2 ----
#pragma unroll
    for (int mt = 0; mt < 4; ++mt) {
      float e0 = __builtin_amdgcn_exp2f(sc[mt][0] - mr);
      float e1 = __builtin_amdgcn_exp2f(sc[mt][1] - mr);
      float e2 = __builtin_amdgcn_exp2f(sc[mt][2] - mr);
      float e3 = __builtin_amdgcn_exp2f(sc[mt][3] - mr);
      h2 a = __builtin_bit_cast(h2, pku(e0, e1));
      h2 bb = __builtin_bit_cast(h2, pku(e2, e3));
      h4 pe = {a[0], a[1], bb[0], bb[1]};
      S1p = fdot2(a, fdot2(bb, S1p));
      h4 p2 = pe * pe, p4 = p2 * p2, p5 = p4 * pe;  // v_pk_mul_f16
      int pcol = (mt * 16 + lg * 4) ^ kxor;
      *(h4*)&Ps[w][0][lq * 64 + pcol] = pe;
      *(h4*)&Ps[w][1][lq * 64 + pcol] = p5;
      if (do5) {
        h2 c = {p5[0], p5[1]}, d = {p5[2], p5[3]};
        S5p = fdot2(c, fdot2(d, S5p));
      }
    }

    // ---- PV: O[q][d] += P V (A = V^T rows d, B = P cols q) ----
    const _Float16* Vts = &kv[cur][1][0];
#pragma unroll
    for (int ks = 0; ks < 2; ++ks) {
      const int rc = (ks * 32 + lg * 8) ^ kxor;
      h8 pb = *(const h8*)&Ps[w][0][lq * 64 + rc];
      __builtin_amdgcn_s_setprio(1);
      if (do5) {
        h8 p5b = *(const h8*)&Ps[w][1][lq * 64 + rc];
#pragma unroll
        for (int dt = 0; dt < 4; ++dt) {
          h8 v = *(const h8*)&Vts[(dt * 16 + lq) * 64 + rc];
          O1[dt] = mm16(v, pb, O1[dt]);
          O5[dt] = mm16(v, p5b, O5[dt]);
        }
      } else {
#pragma unroll
        for (int dt = 0; dt < 4; ++dt) {
          h8 v = *(const h8*)&Vts[(dt * 16 + lq) * 64 + rc];
          O1[dt] = mm16(v, pb, O1[dt]);
        }
      }
      __builtin_amdgcn_s_setprio(0);
    }

    __syncthreads();
  }

  // ---- epilogue: combine partials, out = (O5 + Z^4 O1) / (S5 + Z^4 S1) ----
  float S1 = S1p;
  S1 += __shfl_xor(S1, 16);
  S1 += __shfl_xor(S1, 32);
  float S5 = S5p;
  S5 += __shfl_xor(S5, 16);
  S5 += __shfl_xor(S5, 32);
  const float z = S1, z2 = z * z, z4 = z2 * z2;
  const float inv = 1.0f / (S5 + z4 * S1);
#pragma unroll
  for (int dt = 0; dt < 4; ++dt) {
    f4 o;
#pragma unroll
    for (int j = 0; j < 4; ++j) o[j] = (O5[dt][j] + z4 * O1[dt][j]) * inv;
    *(f4*)(O + base + (size_t)(q0 + lq) * 1024 + dt * 16 + lg * 4) = o;
  }
}

extern "C" void kernel_launch(void* const* d_in, const int* in_sizes, int n_in,
                              void* d_out, int out_size, void* d_ws, size_t ws_size,
                              hipStream_t stream) {
  const float* q = (const float*)d_in[0];
  const float* k = (const float*)d_in[1];
  const float* v = (const float*)d_in[2];
  float* o = (float*)d_out;
  dsa_mfma<<<dim3(512), dim3(512), 0, stream>>>(q, k, v, o);
}

// Round 19
// 80.560 us; speedup vs baseline: 1.4295x; 1.4295x over previous
//
#include <hip/hip_runtime.h>
#include <math.h>

// DynamicSparseAttention via MFMA flash (f16 operands, fp32 accum):
// out = (O5 + Z^4 O1) / (S5 + Z^4 S1), e = 2^(s*log2e - m'), Z = S1.
// R19: final revert to R14/R16 — the measured optimum across every axis
//   tried (MFMA shape, tiles/barrier, staging depth, sums, barrier type,
//   split-K, occupancy). 80.2us, replay-deterministic, no spill.

typedef _Float16 h8 __attribute__((ext_vector_type(8)));
typedef _Float16 h2 __attribute__((ext_vector_type(2)));
typedef __fp16 g2 __attribute__((ext_vector_type(2)));
typedef float f4 __attribute__((ext_vector_type(4)));
typedef float f16v __attribute__((ext_vector_type(16)));
typedef unsigned int u4v __attribute__((ext_vector_type(4)));

constexpr int Sc = 2048, Hc = 16;
constexpr int KB = 64, NT = Sc / KB;
constexpr float LOG2E = 1.4426950408889634f;

__device__ __forceinline__ f16v mm32(h8 a, h8 b, f16v c) {
  return __builtin_amdgcn_mfma_f32_32x32x16_f16(a, b, c, 0, 0, 0);
}
__device__ __forceinline__ unsigned pku(float a, float b) {
  return __builtin_bit_cast(unsigned, __builtin_amdgcn_cvt_pkrtz(a, b));
}
__device__ __forceinline__ float fdot2(h2 a, float c) {  // a.x + a.y + c
  const g2 one2 = {(__fp16)1.0f, (__fp16)1.0f};
  return __builtin_amdgcn_fdot2(__builtin_bit_cast(g2, a), one2, c, false);
}

__global__ __launch_bounds__(256, 2) void dsa_mfma(
    const float* __restrict__ Q, const float* __restrict__ K,
    const float* __restrict__ V, float* __restrict__ O) {
  __shared__ __align__(16) _Float16 smem[4][2][64 * 64];  // [buf][K|V], 64 KB

  const int tid = threadIdx.x;
  const int w = tid >> 6, lane = tid & 63, lm = lane & 31, hi = lane >> 5;
  const int swz = (lm & 7) << 3;

  // XCD-bijective swizzle: 512 blocks = 8 XCD x 64; each XCD owns 4 heads.
  const int blk = blockIdx.x;
  const int ww = (blk & 7) * 64 + (blk >> 3);
  const int qtb = ww & 15, bh = ww >> 4;
  const int b = bh >> 4, h = bh & 15;

  const size_t base = ((size_t)b * Sc * Hc + h) * 64;  // row stride = 1024 floats
  const float* Qb = Q + base;
  const float* Kb = K + base;
  const float* Vb = V + base;
  const int q0 = qtb * 128 + w * 32;

  // ---- Q fragments (B-operand): lane holds Q[q0+lm][s*16 + hi*8 + j]*log2e ----
  h8 qf[4];
#pragma unroll
  for (int s = 0; s < 4; ++s) {
    const float* p = Qb + (size_t)(q0 + lm) * 1024 + s * 16 + hi * 8;
    f4 a = *(const f4*)p, c = *(const f4*)(p + 4);
#pragma unroll
    for (int i = 0; i < 4; ++i) {
      qf[s][i] = (_Float16)(a[i] * LOG2E);
      qf[s][4 + i] = (_Float16)(c[i] * LOG2E);
    }
  }

  f16v O1[2] = {}, O5[2] = {};                     // O^T[d][q], dtile 0/1
  float S1p[2] = {0.f, 0.f}, S5p[2] = {0.f, 0.f};  // fdot2 sum partials
  float mr = -INFINITY;

  // ---- staging: K row-owner (krow=tid&63, 16 floats), V column-gather ----
  f4 kf[4];
  float vreg[2][8];
  const int krow = tid & 63, kq = tid >> 6;       // K: row krow, float cols kq*16..+16
  const int vd = tid & 63, vo0 = (tid >> 6) * 2;  // V: d-col vd, k-octets vo0, vo0+1

  auto LOADK = [&](int k0) {
#pragma unroll
    for (int j = 0; j < 4; ++j)
      kf[j] = *(const f4*)(Kb + (size_t)(k0 + krow) * 1024 + kq * 16 + 4 * j);
  };
  auto LOADV = [&](int k0) {  // coalesced: 64 lanes read consecutive d
#pragma unroll
    for (int i = 0; i < 2; ++i) {
      const float* p = Vb + (size_t)(k0 + (vo0 + i) * 8) * 1024 + vd;
#pragma unroll
      for (int j = 0; j < 8; ++j) vreg[i][j] = p[(size_t)j * 1024];
    }
  };
  auto STORE = [&](int buf) {
    _Float16* Ks = &smem[buf][0][0];
    _Float16* Vts = &smem[buf][1][0];
#pragma unroll
    for (int i = 0; i < 2; ++i) {  // K: two b128 stores
      u4v wv = {pku(kf[2 * i][0], kf[2 * i][1]), pku(kf[2 * i][2], kf[2 * i][3]),
                pku(kf[2 * i + 1][0], kf[2 * i + 1][1]), pku(kf[2 * i + 1][2], kf[2 * i + 1][3])};
      int col = (kq * 16 + 8 * i) ^ ((krow & 7) << 3);
      *(h8*)&Ks[krow * 64 + col] = __builtin_bit_cast(h8, wv);
    }
#pragma unroll
    for (int i = 0; i < 2; ++i) {  // V^T: b128 stores
      u4v wv = {pku(vreg[i][0], vreg[i][1]), pku(vreg[i][2], vreg[i][3]),
                pku(vreg[i][4], vreg[i][5]), pku(vreg[i][6], vreg[i][7])};
      int col = ((vo0 + i) * 8) ^ ((vd & 7) << 3);
      *(h8*)&Vts[vd * 64 + col] = __builtin_bit_cast(h8, wv);
    }
  };

  auto QK = [&](int cur, f16v sc[2]) {
    const _Float16* Ks = &smem[cur][0][0];
    sc[0] = f16v{};
    sc[1] = f16v{};
    __builtin_amdgcn_s_setprio(1);
#pragma unroll
    for (int s = 0; s < 4; ++s) {
      h8 a0 = *(const h8*)&Ks[lm * 64 + ((s * 16 + hi * 8) ^ swz)];
      h8 a1 = *(const h8*)&Ks[(32 + lm) * 64 + ((s * 16 + hi * 8) ^ swz)];
      sc[0] = mm32(a0, qf[s], sc[0]);
      sc[1] = mm32(a1, qf[s], sc[1]);
    }
    __builtin_amdgcn_s_setprio(0);
  };

  auto PVX = [&](int cur, f16v sc[2], bool do5) {  // exp, in-reg P frags, PV + sums
    const _Float16* Vts = &smem[cur][1][0];
#pragma unroll
    for (int s = 0; s < 4; ++s) {
      const int kh = s >> 1, s8 = (s & 1) * 8, par = s & 1;
      float e[8];
#pragma unroll
      for (int j = 0; j < 8; ++j) e[j] = __builtin_amdgcn_exp2f(sc[kh][s8 + j] - mr);
      auto rA = __builtin_amdgcn_permlane32_swap(pku(e[0], e[1]), pku(e[4], e[5]), false, false);
      auto rB = __builtin_amdgcn_permlane32_swap(pku(e[2], e[3]), pku(e[6], e[7]), false, false);
      u4v bwE = {(unsigned)rA[0], (unsigned)rB[0], (unsigned)rA[1], (unsigned)rB[1]};
      h8 bE = __builtin_bit_cast(h8, bwE);
      h8 b2 = bE * bE, b4 = b2 * b2, b5 = b4 * bE;  // v_pk_mul_f16

      // S1 partial: every f16 in bE belongs to this lane's query (col = lm)
      float sp = fdot2(h2{bE[0], bE[1]}, 0.f);
      sp = fdot2(h2{bE[2], bE[3]}, sp);
      sp = fdot2(h2{bE[4], bE[5]}, sp);
      sp = fdot2(h2{bE[6], bE[7]}, sp);
      S1p[par] += sp;

      h8 v0 = *(const h8*)&Vts[lm * 64 + ((s * 16 + hi * 8) ^ swz)];
      h8 v1 = *(const h8*)&Vts[(32 + lm) * 64 + ((s * 16 + hi * 8) ^ swz)];
      __builtin_amdgcn_s_setprio(1);
      O1[0] = mm32(v0, bE, O1[0]);
      O1[1] = mm32(v1, bE, O1[1]);
      if (do5) {  // wave-uniform; skipped terms are exact +0
        float s5 = fdot2(h2{b5[0], b5[1]}, 0.f);
        s5 = fdot2(h2{b5[2], b5[3]}, s5);
        s5 = fdot2(h2{b5[4], b5[5]}, s5);
        s5 = fdot2(h2{b5[6], b5[7]}, s5);
        S5p[par] += s5;
        O5[0] = mm32(v0, b5, O5[0]);
        O5[1] = mm32(v1, b5, O5[1]);
      }
      __builtin_amdgcn_s_setprio(0);
    }
  };

  // ---- prologue: fill buffers 0,1; tile 2 in regs ----
  LOADK(0);
  LOADV(0);
  STORE(0);
  LOADK(KB);
  LOADV(KB);
  STORE(1);
  LOADK(2 * KB);
  LOADV(2 * KB);
  __syncthreads();

  // ---- main loop: 2 tiles per barrier; reads {t,t+1}&3, stores {t+2,t+3}&3 ----
#pragma unroll 1
  for (int t = 0; t < NT; t += 2) {
    if (t + 2 < NT) STORE((t + 2) & 3);
    if (t + 3 < NT) {
      LOADK((t + 3) * KB);
      LOADV((t + 3) * KB);
    }

    f16v s0[2], s1[2];
    QK(t & 3, s0);
    QK((t + 1) & 3, s1);

    // combined max over both tiles (128 k), single rescale check
    float m16[16];
#pragma unroll
    for (int r = 0; r < 16; ++r)
      m16[r] = fmaxf(fmaxf(s0[0][r], s0[1][r]), fmaxf(s1[0][r], s1[1][r]));
#pragma unroll
    for (int d = 8; d >= 1; d >>= 1)
#pragma unroll
      for (int r = 0; r < d; ++r) m16[r] = fmaxf(m16[r], m16[r + d]);
    float tm = fmaxf(m16[0], __shfl_xor(m16[0], 32));
    if (__any(tm > mr)) {
      float nm = fmaxf(mr, tm);
      float f = __builtin_amdgcn_exp2f(mr - nm);
      float f2 = f * f, f5 = f2 * f2 * f;
      mr = nm;
      S1p[0] *= f;
      S1p[1] *= f;
      S5p[0] *= f5;
      S5p[1] *= f5;
#pragma unroll
      for (int dt = 0; dt < 2; ++dt) {
        O1[dt] *= f;
        O5[dt] *= f5;
      }
    }
    // skip e5 accumulation iff 5*(tm-mr) <= -24.5: all f16 e^5 are exact +0
    const bool do5 = __any(tm > mr - 4.9f);

    PVX(t & 3, s0, do5);

    if (t + 3 < NT) STORE((t + 3) & 3);
    if (t + 4 < NT) {
      LOADK((t + 4) * KB);
      LOADV((t + 4) * KB);
    }

    PVX((t + 1) & 3, s1, do5);

    __syncthreads();
  }

  // ---- epilogue: combine partials, out = (O5 + Z^4 O1) / (S5 + Z^4 S1) ----
  float S1 = S1p[0] + S1p[1];
  S1 += __shfl_xor(S1, 32);
  float S5 = S5p[0] + S5p[1];
  S5 += __shfl_xor(S5, 32);
  const float z = S1, z2 = z * z, z4 = z2 * z2;
  const float inv = 1.0f / (S5 + z4 * S1);
#pragma unroll
  for (int dt = 0; dt < 2; ++dt)
#pragma unroll
    for (int i = 0; i < 4; ++i) {
      f4 o;
#pragma unroll
      for (int j = 0; j < 4; ++j)
        o[j] = (O5[dt][4 * i + j] + z4 * O1[dt][4 * i + j]) * inv;
      *(f4*)(O + base + (size_t)(q0 + lm) * 1024 + dt * 32 + 8 * i + 4 * hi) = o;
    }
}

extern "C" void kernel_launch(void* const* d_in, const int* in_sizes, int n_in,
                              void* d_out, int out_size, void* d_ws, size_t ws_size,
                              hipStream_t stream) {
  const float* q = (const float*)d_in[0];
  const float* k = (const float*)d_in[1];
  const float* v = (const float*)d_in[2];
  float* o = (float*)d_out;
  dsa_mfma<<<dim3(512), dim3(256), 0, stream>>>(q, k, v, o);
}